// Round 2
// baseline (213.441 us; speedup 1.0000x reference)
//
#include <hip/hip_runtime.h>

#define H  256
#define W  256
#define S  4
#define OH (H * S)
#define OW (W * S)

typedef float f32x4 __attribute__((ext_vector_type(4)));
// dword-aligned vector type for the unaligned 4-tap window load
typedef f32x4 __attribute__((aligned(4))) f32x4_u;

// Thread = one input column (iw), a slab of 4 consecutive input rows.
// Horizontal-first factoring: filter each of the 7 covered input rows into its
// 4 horizontal sub-pixel phases once (112 FMA), then every output float4 is a
// 4-tap vertical combine (16 FMA). 368 FMA/thread vs 512 in the round-0 version.
// Interior lanes fetch the 4-tap window as one dwordx4; output uses nt stores
// (192 MiB streaming, zero reuse -> don't thrash L2).
__global__ __launch_bounds__(256) void bicubic_up4(
    const float* __restrict__ x, const float* __restrict__ kern,
    float* __restrict__ out)
{
    const int iw  = threadIdx.x;        // input column 0..255
    const int ihb = blockIdx.x * 4;     // first input row of this slab
    const int nc  = blockIdx.y;         // n*c 0..47

    // 16 filter taps (4 phases x 4 taps) — uniform address, scalarized to SGPRs
    float kk[16];
#pragma unroll
    for (int i = 0; i < 16; ++i) kk[i] = kern[i];

    const float* __restrict__ xp = x + (size_t)nc * (H * W);

    // horizontal taps live at cols iw-1 .. iw+2 (replicate clamp at borders)
    const bool interior = (iw >= 1) && (iw <= W - 3);
    const int c0 = max(iw - 1, 0);
    const int c2 = min(iw + 1, W - 1);
    const int c3 = min(iw + 2, W - 1);

    // Horizontal pass over the 7 rows covering the slab's vertical windows.
    float hb[7][4];
#pragma unroll
    for (int t = 0; t < 7; ++t) {
        int r = ihb - 1 + t;
        r = r < 0 ? 0 : (r > H - 1 ? H - 1 : r);
        const float* __restrict__ row = xp + r * W;
        float a, b, c, d;
        if (interior) {
            f32x4 v = *reinterpret_cast<const f32x4_u*>(row + (iw - 1));
            a = v.x; b = v.y; c = v.z; d = v.w;
        } else {
            a = row[c0]; b = row[iw]; c = row[c2]; d = row[c3];
        }
#pragma unroll
        for (int ph = 0; ph < 4; ++ph)
            hb[t][ph] = a * kk[ph * 4 + 0] + b * kk[ph * 4 + 1]
                      + c * kk[ph * 4 + 2] + d * kk[ph * 4 + 3];
    }

    float* __restrict__ obase =
        out + ((size_t)nc * OH + (size_t)ihb * S) * OW + (size_t)iw * S;

#pragma unroll
    for (int q = 0; q < 4; ++q) {          // input row within the slab
#pragma unroll
        for (int kv = 0; kv < 4; ++kv) {   // vertical sub-pixel phase
            const float w0 = kk[kv * 4 + 0];
            const float w1 = kk[kv * 4 + 1];
            const float w2 = kk[kv * 4 + 2];
            const float w3 = kk[kv * 4 + 3];
            f32x4 o;
            o.x = hb[q][0]*w0 + hb[q+1][0]*w1 + hb[q+2][0]*w2 + hb[q+3][0]*w3;
            o.y = hb[q][1]*w0 + hb[q+1][1]*w1 + hb[q+2][1]*w2 + hb[q+3][1]*w3;
            o.z = hb[q][2]*w0 + hb[q+1][2]*w1 + hb[q+2][2]*w2 + hb[q+3][2]*w3;
            o.w = hb[q][3]*w0 + hb[q+1][3]*w1 + hb[q+2][3]*w2 + hb[q+3][3]*w3;
            __builtin_nontemporal_store(
                o, reinterpret_cast<f32x4*>(obase + ((size_t)(q * S + kv)) * OW));
        }
    }
}

extern "C" void kernel_launch(void* const* d_in, const int* in_sizes, int n_in,
                              void* d_out, int out_size, void* d_ws, size_t ws_size,
                              hipStream_t stream) {
    const float* x    = (const float*)d_in[0];
    const float* kern = (const float*)d_in[1];
    float* out        = (float*)d_out;

    dim3 grid(H / 4, 16 * 3);   // 64 x 48 blocks
    dim3 block(256);            // one thread per input column
    bicubic_up4<<<grid, block, 0, stream>>>(x, kern, out);
}